// Round 10
// baseline (297.693 us; speedup 1.0000x reference)
//
#include <hip/hip_runtime.h>
#include <math.h>

#define N 8192
#define D 1024
#define INV_T 14.285714285714286f   // 1/0.07; also the fixed LSE max (|cos|<=1)

typedef unsigned short ushortT;
typedef unsigned int uintT;
typedef __bf16 bf16x8 __attribute__((ext_vector_type(8)));
typedef float f32x4 __attribute__((ext_vector_type(4)));

#define AS1 __attribute__((address_space(1)))
#define AS3 __attribute__((address_space(3)))

__device__ __forceinline__ ushortT f2bf(float x) {
    uintT u = __float_as_uint(x);
    return (ushortT)((u + 0x7fffu + ((u >> 16) & 1u)) >> 16);   // RNE
}

// ===========================================================================
// Kernel 1: wave-per-row L2-normalize (no LDS, no syncthreads).
// 2048 blocks x 256 thr = 4 waves/block, 1 row/wave; 16 f32/lane.
// Also zero-inits rowsum/colsum and seeds out[0] = INV_T.
// ===========================================================================
__global__ __launch_bounds__(256)
void normalize_bf16_kernel(const float* __restrict__ q, const float* __restrict__ k,
                           ushortT* __restrict__ qh, ushortT* __restrict__ kh,
                           float* __restrict__ diag,
                           float* __restrict__ rowsum, float* __restrict__ colsum,
                           float* __restrict__ out) {
    const int wid  = threadIdx.x >> 6;
    const int lane = threadIdx.x & 63;
    const int row  = blockIdx.x * 4 + wid;
    if (lane == 60) rowsum[row] = 0.f;
    if (lane == 61) colsum[row] = 0.f;
    if (row == 0 && lane == 62) out[0] = INV_T;

    const float* qr = q + (size_t)row * D;
    const float* kr = k + (size_t)row * D;
    float4 a[4], b[4];
    #pragma unroll
    for (int j = 0; j < 4; ++j) {
        a[j] = *(const float4*)(qr + j * 256 + lane * 4);
        b[j] = *(const float4*)(kr + j * 256 + lane * 4);
    }
    float sqq = 0.f, skk = 0.f, sqk = 0.f;
    #pragma unroll
    for (int j = 0; j < 4; ++j) {
        sqq += a[j].x*a[j].x + a[j].y*a[j].y + a[j].z*a[j].z + a[j].w*a[j].w;
        skk += b[j].x*b[j].x + b[j].y*b[j].y + b[j].z*b[j].z + b[j].w*b[j].w;
        sqk += a[j].x*b[j].x + a[j].y*b[j].y + a[j].z*b[j].z + a[j].w*b[j].w;
    }
    #pragma unroll
    for (int m = 1; m < 64; m <<= 1) {
        sqq += __shfl_xor(sqq, m, 64);
        skk += __shfl_xor(skk, m, 64);
        sqk += __shfl_xor(sqk, m, 64);
    }
    const float iq = 1.0f / fmaxf(sqrtf(sqq), 1e-12f);
    const float ik = 1.0f / fmaxf(sqrtf(skk), 1e-12f);
    if (lane == 0) diag[row] = sqk * iq * ik * INV_T;   // exact fp32 diagonal

    #pragma unroll
    for (int j = 0; j < 4; ++j) {
        float av[4] = {a[j].x * iq, a[j].y * iq, a[j].z * iq, a[j].w * iq};
        float bv[4] = {b[j].x * ik, b[j].y * ik, b[j].z * ik, b[j].w * ik};
        ushort4 qv, kv;
        ushortT* qp = (ushortT*)&qv; ushortT* kp = (ushortT*)&kv;
        #pragma unroll
        for (int e = 0; e < 4; ++e) { qp[e] = f2bf(av[e]); kp[e] = f2bf(bv[e]); }
        *(ushort4*)(qh + (size_t)row * D + j * 256 + lane * 4) = qv;
        *(ushort4*)(kh + (size_t)row * D + j * 256 + lane * 4) = kv;
    }
}

// ===========================================================================
// Kernel 2: 256x256-tile bf16 MFMA GEMM, fused exp + row/col sums.
// 8 waves (2M x 4N), wave-tile 128x64, BK=64, LDS 2x64KB dbuf, all 8 staging
// loads at tile start (3-phase flight -> tile-end vmcnt(0) pre-satisfied).
// NEW: 4 fine phases per K-tile {reads -> bar -> setprio+16 MFMA -> bar} so
// per-wave read batches are small and LDS-queue stagger overlaps reads with
// MFMA across waves (m196/m201 mechanism). Proven slot^=(r&7) swizzle.
// ===========================================================================
#define LBUF 65536
#define NT 16

__global__ __launch_bounds__(512, 2)
void mfma256_lse_kernel(const ushortT* __restrict__ qh, const ushortT* __restrict__ kh,
                        float* __restrict__ rowsum, float* __restrict__ colsum) {
    __shared__ __align__(16) char lds[2 * LBUF];   // [buf][A 32KB | B 32KB]

    // bijective XCD-chunked swizzle: 1024 wgs, 8 XCDs, 128 per XCD
    const int wg  = blockIdx.x;
    const int swz = (wg & 7) * 128 + (wg >> 3);
    const int bi  = swz >> 5;
    const int bj  = swz & 31;

    const int tid  = threadIdx.x;
    const int w    = tid >> 6;
    const int lane = tid & 63;
    const int wm   = w >> 2, wn = w & 3;       // wave grid 2M x 4N
    const int la   = lane & 15, lq = lane >> 4;

    // --- staging: pre-swizzled global element offsets (16B granules) ---
    size_t aoff[4], boff[4];
    int dstb[4];
    #pragma unroll
    for (int i = 0; i < 4; ++i) {
        int lin = i * 512 + tid;
        int r   = lin >> 3;
        int s   = lin & 7;
        int sp  = s ^ (r & 7);
        aoff[i] = (size_t)(bi * 256 + r) * D + sp * 8;
        boff[i] = (size_t)(bj * 256 + r) * D + sp * 8;
        dstb[i] = lin * 16;
    }

    // --- fragment LDS byte offsets (K-independent, relative to buf base) ---
    int byteA[8][2], byteB[4][2];
    #pragma unroll
    for (int f = 0; f < 8; ++f) {
        int ra = wm * 128 + f * 16 + la;
        byteA[f][0] = ra * 128 + ((lq       ^ (ra & 7)) * 16);
        byteA[f][1] = ra * 128 + (((lq ^ 4) ^ (ra & 7)) * 16);
    }
    #pragma unroll
    for (int n = 0; n < 4; ++n) {
        int rb = wn * 64 + n * 16 + la;
        byteB[n][0] = 32768 + rb * 128 + ((lq       ^ (rb & 7)) * 16);
        byteB[n][1] = 32768 + rb * 128 + (((lq ^ 4) ^ (rb & 7)) * 16);
    }

    f32x4 acc[8][4] = {};

#define STAGE(t1) do { \
    char* db_ = lds + (((t1) & 1) * LBUF); \
    const size_t kof_ = (size_t)(t1) * 64; \
    _Pragma("unroll") \
    for (int i_ = 0; i_ < 4; ++i_) { \
        __builtin_amdgcn_global_load_lds( \
            (const AS1 void*)(qh + aoff[i_] + kof_), \
            (AS3 void*)(db_ + dstb[i_]), 16, 0, 0); \
        __builtin_amdgcn_global_load_lds( \
            (const AS1 void*)(kh + boff[i_] + kof_), \
            (AS3 void*)(db_ + 32768 + dstb[i_]), 16, 0, 0); \
    } } while (0)

#define BAR() __builtin_amdgcn_s_barrier()

    // ---- prologue: stage tile 0 ----
    STAGE(0);
    asm volatile("s_waitcnt vmcnt(0)" ::: "memory");
    BAR();

    #pragma unroll 1
    for (int t = 0; t < NT; ++t) {
        const char* bufb = lds + (t & 1) * LBUF;

        if (t < NT - 1) STAGE(t + 1);     // 8 loads, full-tile flight

        bf16x8 bk[4], aF[4];

        // ---- P1: (m0-3, k0) ----
        #pragma unroll
        for (int n = 0; n < 4; ++n) bk[n] = *(const bf16x8*)(bufb + byteB[n][0]);
        #pragma unroll
        for (int f = 0; f < 4; ++f) aF[f] = *(const bf16x8*)(bufb + byteA[f][0]);
        BAR();
        __builtin_amdgcn_s_setprio(1);
        #pragma unroll
        for (int f = 0; f < 4; ++f)
            #pragma unroll
            for (int n = 0; n < 4; ++n)
                acc[f][n] = __builtin_amdgcn_mfma_f32_16x16x32_bf16(aF[f], bk[n], acc[f][n], 0, 0, 0);
        __builtin_amdgcn_s_setprio(0);
        BAR();

        // ---- P2: (m4-7, k0) ----
        #pragma unroll
        for (int f = 0; f < 4; ++f) aF[f] = *(const bf16x8*)(bufb + byteA[f + 4][0]);
        BAR();
        __builtin_amdgcn_s_setprio(1);
        #pragma unroll
        for (int f = 0; f < 4; ++f)
            #pragma unroll
            for (int n = 0; n < 4; ++n)
                acc[f + 4][n] = __builtin_amdgcn_mfma_f32_16x16x32_bf16(aF[f], bk[n], acc[f + 4][n], 0, 0, 0);
        __builtin_amdgcn_s_setprio(0);
        BAR();

        // ---- P3: (m0-3, k1) ----
        #pragma unroll
        for (int n = 0; n < 4; ++n) bk[n] = *(const bf16x8*)(bufb + byteB[n][1]);
        #pragma unroll
        for (int f = 0; f < 4; ++f) aF[f] = *(const bf16x8*)(bufb + byteA[f][1]);
        BAR();
        __builtin_amdgcn_s_setprio(1);
        #pragma unroll
        for (int f = 0; f < 4; ++f)
            #pragma unroll
            for (int n = 0; n < 4; ++n)
                acc[f][n] = __builtin_amdgcn_mfma_f32_16x16x32_bf16(aF[f], bk[n], acc[f][n], 0, 0, 0);
        __builtin_amdgcn_s_setprio(0);
        BAR();

        // ---- P4: (m4-7, k1) ----
        #pragma unroll
        for (int f = 0; f < 4; ++f) aF[f] = *(const bf16x8*)(bufb + byteA[f + 4][1]);
        BAR();
        __builtin_amdgcn_s_setprio(1);
        #pragma unroll
        for (int f = 0; f < 4; ++f)
            #pragma unroll
            for (int n = 0; n < 4; ++n)
                acc[f + 4][n] = __builtin_amdgcn_mfma_f32_16x16x32_bf16(aF[f], bk[n], acc[f + 4][n], 0, 0, 0);
        __builtin_amdgcn_s_setprio(0);
        // tile boundary: next tile's loads have ~3 phases of flight
        asm volatile("s_waitcnt vmcnt(0)" ::: "memory");
        BAR();
    }
#undef STAGE
#undef BAR

    // --- epilogue: e = exp((cos-1)/T); row/col partial sums; atomics ---
    #pragma unroll
    for (int f = 0; f < 8; ++f)
        #pragma unroll
        for (int n = 0; n < 4; ++n)
            #pragma unroll
            for (int r = 0; r < 4; ++r)
                acc[f][n][r] = __expf((acc[f][n][r] - 1.0f) * INV_T);

    // rows: global row = bi*256 + wm*128 + f*16 + lq*4 + r; reduce over la
    #pragma unroll
    for (int f = 0; f < 8; ++f)
        #pragma unroll
        for (int r = 0; r < 4; ++r) {
            float v = acc[f][0][r] + acc[f][1][r] + acc[f][2][r] + acc[f][3][r];
            v += __shfl_xor(v, 1, 64);
            v += __shfl_xor(v, 2, 64);
            v += __shfl_xor(v, 4, 64);
            v += __shfl_xor(v, 8, 64);
            if (la == 0)
                atomicAdd(&rowsum[bi * 256 + wm * 128 + f * 16 + lq * 4 + r], v);
        }

    // cols: global col = bj*256 + wn*64 + n*16 + la; reduce over lq
    #pragma unroll
    for (int n = 0; n < 4; ++n) {
        float v = 0.f;
        #pragma unroll
        for (int f = 0; f < 8; ++f)
            #pragma unroll
            for (int r = 0; r < 4; ++r)
                v += acc[f][n][r];
        v += __shfl_xor(v, 16, 64);
        v += __shfl_xor(v, 32, 64);
        if (lq == 0)
            atomicAdd(&colsum[bj * 256 + wn * 64 + n * 16 + la], v);
    }
}

// ===========================================================================
// Kernel 3: out += sum(0.5*(log rs + log cs) - diag)/N  (out pre-seeded INV_T)
// ===========================================================================
__global__ __launch_bounds__(1024)
void final_kernel(const float* __restrict__ rowsum, const float* __restrict__ colsum,
                  const float* __restrict__ diag, float* __restrict__ out) {
    const int tid = threadIdx.x;
    const int i = blockIdx.x * 1024 + tid;
    float p = 0.5f * (logf(rowsum[i]) + logf(colsum[i])) - diag[i];
    #pragma unroll
    for (int m = 1; m < 64; m <<= 1) p += __shfl_xor(p, m, 64);
    __shared__ float red[16];
    const int wid = tid >> 6, lane = tid & 63;
    if (lane == 0) red[wid] = p;
    __syncthreads();
    if (tid == 0) {
        float t = 0.f;
        #pragma unroll
        for (int w = 0; w < 16; ++w) t += red[w];
        atomicAdd(out, t / (float)N);
    }
}

// ===========================================================================
// FALLBACK PATH (fp32 VALU GEMM, needs only 5*N floats of ws)
// ===========================================================================
#define BT 128
__global__ __launch_bounds__(256)
void norms_diag_kernel(const float* __restrict__ q, const float* __restrict__ k,
                       float* __restrict__ invq, float* __restrict__ invk,
                       float* __restrict__ diag, float* __restrict__ out) {
    const int row = blockIdx.x;
    const int tid = threadIdx.x;
    if (row == 0 && tid == 66) out[0] = INV_T;
    float4 a = *(const float4*)(q + (size_t)row * D + tid * 4);
    float4 b = *(const float4*)(k + (size_t)row * D + tid * 4);
    float sqq = a.x*a.x + a.y*a.y + a.z*a.z + a.w*a.w;
    float skk = b.x*b.x + b.y*b.y + b.z*b.z + b.w*b.w;
    float sqk = a.x*b.x + a.y*b.y + a.z*b.z + a.w*b.w;
    #pragma unroll
    for (int m = 1; m < 64; m <<= 1) {
        sqq += __shfl_xor(sqq, m, 64);
        skk += __shfl_xor(skk, m, 64);
        sqk += __shfl_xor(sqk, m, 64);
    }
    __shared__ float red[3][4];
    const int wid = tid >> 6, lane = tid & 63;
    if (lane == 0) { red[0][wid] = sqq; red[1][wid] = skk; red[2][wid] = sqk; }
    __syncthreads();
    if (tid == 0) {
        float s0 = red[0][0] + red[0][1] + red[0][2] + red[0][3];
        float s1 = red[1][0] + red[1][1] + red[1][2] + red[1][3];
        float s2 = red[2][0] + red[2][1] + red[2][2] + red[2][3];
        float iq = 1.0f / fmaxf(sqrtf(s0), 1e-12f);
        float ik = 1.0f / fmaxf(sqrtf(s1), 1e-12f);
        invq[row] = iq; invk[row] = ik;
        diag[row] = s2 * iq * ik * INV_T;
    }
}

#define KBF 16
#define LDTF 132
__global__ __launch_bounds__(256)
void gemm_lse_kernel(const float* __restrict__ q, const float* __restrict__ k,
                     const float* __restrict__ invq, const float* __restrict__ invk,
                     float* __restrict__ rowsum, float* __restrict__ colsum) {
    __shared__ float As[KBF * LDTF];
    __shared__ float Bs[KBF * LDTF];
    const int tid = threadIdx.x;
    const int tx = tid & 15;
    const int ty = tid >> 4;
    const int bi = blockIdx.y;
    const int bj = blockIdx.x;
    const float* qb = q + (size_t)(bi * BT) * D;
    const float* kb = k + (size_t)(bj * BT) * D;
    float acc[8][8] = {};
    for (int k0 = 0; k0 < D; k0 += KBF) {
        #pragma unroll
        for (int i = 0; i < 2; ++i) {
            int idx  = tid + i * 256;
            int row  = idx >> 2;
            int kc4  = idx & 3;
            float4 av = *(const float4*)(qb + (size_t)row * D + k0 + kc4 * 4);
            float4 bv = *(const float4*)(kb + (size_t)row * D + k0 + kc4 * 4);
            int base = (kc4 * 4) * LDTF + row;
            As[base] = av.x; As[base + LDTF] = av.y; As[base + 2*LDTF] = av.z; As[base + 3*LDTF] = av.w;
            Bs[base] = bv.x; Bs[base + LDTF] = bv.y; Bs[base + 2*LDTF] = bv.z; Bs[base + 3*LDTF] = bv.w;
        }
        __syncthreads();
        #pragma unroll
        for (int kk = 0; kk < KBF; ++kk) {
            const float* ap = &As[kk * LDTF + ty * 8];
            const float* bp = &Bs[kk * LDTF + tx * 8];
            float4 a0 = *(const float4*)(ap);
            float4 a1 = *(const float4*)(ap + 4);
            float4 b0 = *(const float4*)(bp);
            float4 b1 = *(const float4*)(bp + 4);
            float ar[8] = {a0.x, a0.y, a0.z, a0.w, a1.x, a1.y, a1.z, a1.w};
            float br[8] = {b0.x, b0.y, b0.z, b0.w, b1.x, b1.y, b1.z, b1.w};
            #pragma unroll
            for (int r = 0; r < 8; ++r)
                #pragma unroll
                for (int c = 0; c < 8; ++c)
                    acc[r][c] += ar[r] * br[c];
        }
        __syncthreads();
    }
    float iqr[8], ikc[8];
    #pragma unroll
    for (int r = 0; r < 8; ++r) iqr[r] = invq[bi * BT + ty * 8 + r] * INV_T;
    #pragma unroll
    for (int c = 0; c < 8; ++c) ikc[c] = invk[bj * BT + tx * 8 + c];
    float rowpart[8] = {};
    float colpart[8] = {};
    #pragma unroll
    for (int r = 0; r < 8; ++r)
        #pragma unroll
        for (int c = 0; c < 8; ++c) {
            float e = __expf(acc[r][c] * iqr[r] * ikc[c] - INV_T);
            rowpart[r] += e; colpart[c] += e;
        }
    #pragma unroll
    for (int r = 0; r < 8; ++r) {
        float v = rowpart[r];
        v += __shfl_xor(v, 1, 64); v += __shfl_xor(v, 2, 64);
        v += __shfl_xor(v, 4, 64); v += __shfl_xor(v, 8, 64);
        if (tx == 0) atomicAdd(&rowsum[bi * BT + ty * 8 + r], v);
    }
    __syncthreads();
    float* colbuf = As;
    #pragma unroll
    for (int c = 0; c < 8; ++c) colbuf[ty * 128 + tx * 8 + c] = colpart[c];
    __syncthreads();
    if (tid < 128) {
        float s = 0.f;
        #pragma unroll
        for (int t2 = 0; t2 < 16; ++t2) s += colbuf[t2 * 128 + tid];
        atomicAdd(&colsum[bj * BT + tid], s);
    }
}

// ===========================================================================
extern "C" void kernel_launch(void* const* d_in, const int* in_sizes, int n_in,
                              void* d_out, int out_size, void* d_ws, size_t ws_size,
                              hipStream_t stream) {
    const float* q = (const float*)d_in[0];
    const float* k = (const float*)d_in[1];

    const size_t planeBytes = 2ull * N * D * sizeof(ushortT);   // 32 MB (qh+kh)
    const size_t needFast   = planeBytes + 3ull * N * sizeof(float);

    if (ws_size >= needFast) {
        ushortT* qh = (ushortT*)d_ws;
        ushortT* kh = qh + (size_t)N * D;
        float* tail  = (float*)((char*)d_ws + planeBytes);
        float* rowsum = tail;
        float* colsum = tail + N;
        float* diag   = tail + 2 * N;

        normalize_bf16_kernel<<<N / 4, 256, 0, stream>>>(q, k, qh, kh, diag,
                                                         rowsum, colsum, (float*)d_out);
        mfma256_lse_kernel<<<(N / 256) * (N / 256), 512, 0, stream>>>(qh, kh, rowsum, colsum);
        final_kernel<<<N / 1024, 1024, 0, stream>>>(rowsum, colsum, diag, (float*)d_out);
    } else {
        float* ws     = (float*)d_ws;
        float* invq   = ws;
        float* invk   = ws + N;
        float* rowsum = ws + 2 * N;
        float* colsum = ws + 3 * N;
        float* diag   = ws + 4 * N;
        hipMemsetAsync(rowsum, 0, 2ull * N * sizeof(float), stream);
        norms_diag_kernel<<<N, 256, 0, stream>>>(q, k, invq, invk, diag, (float*)d_out);
        gemm_lse_kernel<<<dim3(N / BT, N / BT), 256, 0, stream>>>(q, k, invq, invk, rowsum, colsum);
        final_kernel<<<N / 1024, 1024, 0, stream>>>(rowsum, colsum, diag, (float*)d_out);
    }
}